// Round 2
// baseline (396.706 us; speedup 1.0000x reference)
//
#include <hip/hip_runtime.h>
#include <hip/hip_bf16.h>

// Flash attention fwd, masked, fp32 I/O, bf16 MFMA compute.
// n=8 heads, q=s=4096, d=v=64.
// Layout trick: compute S^T = K·Q^T so each lane owns one q-column
// (q = lane&15); softmax m/l reduce is 2 shuffles; PV computes O^T = V^T·P^T.
// Mask dtype (bool-as-u8 vs int32 vs f32) detected at runtime on device.

#define NHEADS 8
#define QLEN   4096
#define SLEN   4096
#define DDIM   64
#define VDIM   64
#define SBLK   64
#define QBLK   64     // per block: 4 waves x 16 q-rows
#define NWAVES 4

typedef __bf16          bf16x8 __attribute__((ext_vector_type(8)));
typedef float           f32x4  __attribute__((ext_vector_type(4)));
typedef unsigned int    u32x4  __attribute__((ext_vector_type(4)));
typedef unsigned short  u16x4  __attribute__((ext_vector_type(4)));
typedef unsigned short  u16x8  __attribute__((ext_vector_type(8)));

__device__ __forceinline__ unsigned short f2bf(float x) {
  unsigned u = __builtin_bit_cast(unsigned, x);
  u += 0x7FFFu + ((u >> 16) & 1u);          // round-to-nearest-even
  return (unsigned short)(u >> 16);
}

// Classify mask element format by byte structure of the first 4096 bytes.
// int32 {0,1}: bytes at offsets 1,2 (mod 4) are all zero.
// f32 {0.0,1.0}: bytes at offsets 0 (mod 4) are all zero (0x3F800000 LE).
// u8 bool {0,1}: neither holds (w.h.p. over 1024 random elements).
__global__ void detect_mask_kernel(const unsigned char* __restrict__ M,
                                   int* __restrict__ flag) {
  __shared__ int or12, or0;
  if (threadIdx.x == 0) { or12 = 0; or0 = 0; }
  __syncthreads();
  int v12 = 0, v0 = 0;
  for (int i = threadIdx.x; i < 1024; i += 256) {
    v12 |= M[4 * i + 1] | M[4 * i + 2];
    v0  |= M[4 * i + 0];
  }
  atomicOr(&or12, v12);
  atomicOr(&or0, v0);
  __syncthreads();
  if (threadIdx.x == 0)
    *flag = (or12 == 0) ? 1 : ((or0 == 0) ? 2 : 0);   // 1=int32/f32-words? no: 1=i32, 2=f32, 0=u8
}

__global__ __launch_bounds__(256, 2)
void attn_fwd_kernel(const float* __restrict__ Qg, const float* __restrict__ Kg,
                     const float* __restrict__ Vg, const unsigned char* __restrict__ Mg,
                     float* __restrict__ Og, const int* __restrict__ mflag)
{
  __shared__ __align__(16) unsigned short Ksh[64 * 64];          // K chunk [s][d], swizzled
  __shared__ __align__(16) unsigned short Vsh[64 * 64];          // V^T chunk [v][s], swizzled
  __shared__ __align__(16) unsigned short Psh[NWAVES][16 * 64];  // P [q][s] per wave, swizzled

  const int mfmt = *mflag;      // uniform scalar

  const int tid  = threadIdx.x;
  const int wave = tid >> 6;
  const int lane = tid & 63;
  const int g    = lane >> 4;   // 16-lane group 0..3
  const int lq   = lane & 15;   // this lane's q column (within wave tile)

  const int head = blockIdx.y;
  const int qblk = blockIdx.x;

  const float* Qp = Qg + ((size_t)head * QLEN + (size_t)qblk * QBLK) * DDIM;
  const float* Kp = Kg + (size_t)head * SLEN * DDIM;
  const float* Vp = Vg + (size_t)head * SLEN * VDIM;
  float* Op = Og + ((size_t)head * QLEN + (size_t)qblk * QBLK) * DDIM;

  // ---- hoist Q fragments to registers (B-frag: col q = lq, k = 8g+32ks+i) ----
  const int qrow = wave * 16 + lq;
  bf16x8 qf[2];
#pragma unroll
  for (int ks = 0; ks < 2; ++ks) {
    const float* qp = Qp + (size_t)qrow * DDIM + 8 * g + 32 * ks;
    f32x4 a = *(const f32x4*)qp;
    f32x4 b = *(const f32x4*)(qp + 4);
    u16x8 t;
    t[0] = f2bf(a[0]); t[1] = f2bf(a[1]); t[2] = f2bf(a[2]); t[3] = f2bf(a[3]);
    t[4] = f2bf(b[0]); t[5] = f2bf(b[1]); t[6] = f2bf(b[2]); t[7] = f2bf(b[3]);
    qf[ks] = __builtin_bit_cast(bf16x8, t);
  }

  const size_t mrow_elems = ((size_t)head * QLEN + (size_t)qblk * QBLK + qrow) * SLEN;
  const unsigned char* mrow8  = Mg + mrow_elems;           // u8 path
  const unsigned*      mrow32 = (const unsigned*)Mg + mrow_elems;  // i32/f32 path

  f32x4 oacc[4];
#pragma unroll
  for (int vt = 0; vt < 4; ++vt) oacc[vt] = (f32x4){0.f, 0.f, 0.f, 0.f};
  float m_run = -INFINITY;
  float l_run = 0.f;

  const float SCALE = 0.125f;        // 1/sqrt(64)
  const float LOG2E = 1.44269504f;

  for (int c = 0; c < SLEN / SBLK; ++c) {
    const int s0c = c * SBLK;

    // ---- stage K chunk [64][64] fp32 -> bf16 LDS (coalesced) ----
#pragma unroll
    for (int it = 0; it < 4; ++it) {
      int srow = (tid >> 4) + it * 16;
      int d0   = (tid & 15) * 4;
      f32x4 kv = *(const f32x4*)(Kp + (size_t)(s0c + srow) * DDIM + d0);
      u16x4 b; b[0] = f2bf(kv[0]); b[1] = f2bf(kv[1]); b[2] = f2bf(kv[2]); b[3] = f2bf(kv[3]);
      int off = (srow * 128 + d0 * 2) ^ ((srow & 7) << 4);
      *(u16x4*)((char*)Ksh + off) = b;
    }
    // ---- stage V^T chunk: Vsh[v][s] (strided global reads, coalesced LDS writes) ----
#pragma unroll
    for (int it = 0; it < 4; ++it) {
      int vv = (tid >> 4) + it * 16;
      int s4 = (tid & 15) * 4;
      const float* vp = Vp + (size_t)(s0c + s4) * VDIM + vv;
      float a0 = vp[0], a1 = vp[VDIM], a2 = vp[2 * VDIM], a3 = vp[3 * VDIM];
      u16x4 b; b[0] = f2bf(a0); b[1] = f2bf(a1); b[2] = f2bf(a2); b[3] = f2bf(a3);
      int off = (vv * 128 + s4 * 2) ^ ((vv & 7) << 4);
      *(u16x4*)((char*)Vsh + off) = b;
    }
    __syncthreads();

    // ---- QK^T: S^T tiles (A = K rows-of-s, B = Q^T) ----
    f32x4 sacc[4];
#pragma unroll
    for (int st = 0; st < 4; ++st) sacc[st] = (f32x4){0.f, 0.f, 0.f, 0.f};
#pragma unroll
    for (int st = 0; st < 4; ++st) {
      int srow = lq + 16 * st;
#pragma unroll
      for (int ks = 0; ks < 2; ++ks) {
        int off = (srow * 128 + (8 * g + 32 * ks) * 2) ^ ((srow & 7) << 4);
        bf16x8 kf = *(const bf16x8*)((const char*)Ksh + off);
        sacc[st] = __builtin_amdgcn_mfma_f32_16x16x32_bf16(kf, qf[ks], sacc[st], 0, 0, 0);
      }
    }

    // ---- scale + mask + chunk max (lane's scores: s = 16st+4g+r, fixed q=lq) ----
    float vals[4][4];
    float mloc = -INFINITY;
#pragma unroll
    for (int st = 0; st < 4; ++st) {
      bool keep[4];
      if (mfmt == 0) {              // u8 bool
        unsigned mb = *(const unsigned*)(mrow8 + s0c + 16 * st + 4 * g);
#pragma unroll
        for (int r = 0; r < 4; ++r) keep[r] = ((mb >> (8 * r)) & 0xFFu) != 0;
      } else {                      // int32 {0,1} or f32 {0.0,1.0}: word != 0
        u32x4 mw = *(const u32x4*)(mrow32 + s0c + 16 * st + 4 * g);
#pragma unroll
        for (int r = 0; r < 4; ++r) keep[r] = mw[r] != 0u;
      }
#pragma unroll
      for (int r = 0; r < 4; ++r) {
        float v = sacc[st][r] * SCALE;
        v = keep[r] ? v : -1.0e9f;
        vals[st][r] = v;
        mloc = fmaxf(mloc, v);
      }
    }
    mloc = fmaxf(mloc, __shfl_xor(mloc, 16));
    mloc = fmaxf(mloc, __shfl_xor(mloc, 32));
    float m_new = fmaxf(m_run, mloc);
    float alpha = __builtin_amdgcn_exp2f((m_run - m_new) * LOG2E);  // -inf -> 0 first iter

    // ---- P = exp(S - m), write bf16 to LDS; accumulate l ----
    float lsum = 0.f;
#pragma unroll
    for (int st = 0; st < 4; ++st) {
      u16x4 pb;
#pragma unroll
      for (int r = 0; r < 4; ++r) {
        float p = __builtin_amdgcn_exp2f((vals[st][r] - m_new) * LOG2E);
        lsum += p;
        pb[r] = f2bf(p);
      }
      int off = (lq * 128 + (16 * st + 4 * g) * 2) ^ ((lq & 7) << 4);
      *(u16x4*)((char*)Psh[wave] + off) = pb;
    }
    lsum += __shfl_xor(lsum, 16);
    lsum += __shfl_xor(lsum, 32);
    l_run = l_run * alpha + lsum;
    m_run = m_new;
#pragma unroll
    for (int vt = 0; vt < 4; ++vt) {
#pragma unroll
      for (int r = 0; r < 4; ++r) oacc[vt][r] *= alpha;
    }

    // ---- PV: O^T += V^T_tile · P^T ----
#pragma unroll
    for (int ks = 0; ks < 2; ++ks) {
      int poff = (lq * 128 + (8 * g + 32 * ks) * 2) ^ ((lq & 7) << 4);
      bf16x8 pf = *(const bf16x8*)((const char*)Psh[wave] + poff);
#pragma unroll
      for (int vt = 0; vt < 4; ++vt) {
        int vrow = lq + 16 * vt;
        int voff = (vrow * 128 + (8 * g + 32 * ks) * 2) ^ ((vrow & 7) << 4);
        bf16x8 vf = *(const bf16x8*)((const char*)Vsh + voff);
        oacc[vt] = __builtin_amdgcn_mfma_f32_16x16x32_bf16(vf, pf, oacc[vt], 0, 0, 0);
      }
    }
    __syncthreads();
  }

  // ---- epilogue: O = O^T(v,q)/l, store fp32 (lane: q=lq fixed, v=16vt+4g+r) ----
  float inv_l = 1.0f / l_run;
  float* orow = Op + (size_t)qrow * VDIM;
#pragma unroll
  for (int vt = 0; vt < 4; ++vt) {
    f32x4 o;
#pragma unroll
    for (int r = 0; r < 4; ++r) o[r] = oacc[vt][r] * inv_l;
    *(f32x4*)(orow + 16 * vt + 4 * g) = o;
  }
}

extern "C" void kernel_launch(void* const* d_in, const int* in_sizes, int n_in,
                              void* d_out, int out_size, void* d_ws, size_t ws_size,
                              hipStream_t stream) {
  const float* Qg = (const float*)d_in[0];
  const float* Kg = (const float*)d_in[1];
  const float* Vg = (const float*)d_in[2];
  const unsigned char* Mg = (const unsigned char*)d_in[3];
  float* Og = (float*)d_out;
  int* mflag = (int*)d_ws;

  detect_mask_kernel<<<1, 256, 0, stream>>>(Mg, mflag);

  dim3 grid(QLEN / QBLK, NHEADS);
  dim3 block(256);
  attn_fwd_kernel<<<grid, block, 0, stream>>>(Qg, Kg, Vg, Mg, Og, mflag);
}

// Round 3
// 332.296 us; speedup vs baseline: 1.1938x; 1.1938x over previous
//
#include <hip/hip_runtime.h>
#include <hip/hip_bf16.h>

// Flash attention fwd, masked, fp32 I/O, bf16 MFMA compute.
// n=8 heads, q=s=4096, d=v=64.
// S^T = K·Q^T so each lane owns one q-column; PV computes O^T = V^T·P^T.
// Round 3: software pipeline — double-buffered K/V LDS (1 barrier/chunk),
// next-chunk K/V+mask prefetched into registers, scale*log2e folded into Q.

#define NHEADS 8
#define QLEN   4096
#define SLEN   4096
#define DDIM   64
#define VDIM   64
#define SBLK   64
#define QBLK   64     // per block: 4 waves x 16 q-rows
#define NWAVES 4
#define NCHUNK (SLEN / SBLK)

typedef __bf16          bf16x4 __attribute__((ext_vector_type(4)));
typedef __bf16          bf16x8 __attribute__((ext_vector_type(8)));
typedef float           f32x4  __attribute__((ext_vector_type(4)));
typedef unsigned int    u32x4  __attribute__((ext_vector_type(4)));
typedef unsigned short  u16x4  __attribute__((ext_vector_type(4)));

// Classify mask element format by byte structure of the first 4096 bytes.
// int32 {0,1}: bytes at offsets 1,2 (mod 4) all zero.
// f32 {0.0,1.0}: bytes at offset 0 (mod 4) all zero (0x3F800000 LE).
// u8 bool {0,1}: neither (w.h.p. over 1024 random elements).
__global__ void detect_mask_kernel(const unsigned char* __restrict__ M,
                                   int* __restrict__ flag) {
  __shared__ int or12, or0;
  if (threadIdx.x == 0) { or12 = 0; or0 = 0; }
  __syncthreads();
  int v12 = 0, v0 = 0;
  for (int i = threadIdx.x; i < 1024; i += 256) {
    v12 |= M[4 * i + 1] | M[4 * i + 2];
    v0  |= M[4 * i + 0];
  }
  atomicOr(&or12, v12);
  atomicOr(&or0, v0);
  __syncthreads();
  if (threadIdx.x == 0)
    *flag = (or12 == 0) ? 1 : ((or0 == 0) ? 2 : 0);   // 1=i32, 2=f32, 0=u8
}

struct MaskRegs {
  unsigned w8[4];
  u32x4    w32[4];
};

__global__ __launch_bounds__(256, 2)
void attn_fwd_kernel(const float* __restrict__ Qg, const float* __restrict__ Kg,
                     const float* __restrict__ Vg, const unsigned char* __restrict__ Mg,
                     float* __restrict__ Og, const int* __restrict__ mflag)
{
  __shared__ __align__(16) unsigned short Ksh[2][64 * 64];       // K chunk [s][d], swizzled
  __shared__ __align__(16) unsigned short Vsh[2][64 * 64];       // V^T chunk [v][s], swizzled
  __shared__ __align__(16) unsigned short Psh[NWAVES][16 * 64];  // P [q][s] per wave, swizzled

  const int mfmt = *mflag;      // uniform scalar

  const int tid  = threadIdx.x;
  const int wave = tid >> 6;
  const int lane = tid & 63;
  const int g    = lane >> 4;   // 16-lane group 0..3
  const int lq   = lane & 15;   // this lane's q column (within wave tile)

  const int head = blockIdx.y;
  const int qblk = blockIdx.x;

  const float* Qp = Qg + ((size_t)head * QLEN + (size_t)qblk * QBLK) * DDIM;
  const float* Kp = Kg + (size_t)head * SLEN * DDIM;
  const float* Vp = Vg + (size_t)head * SLEN * VDIM;
  float* Op = Og + ((size_t)head * QLEN + (size_t)qblk * QBLK) * DDIM;

  // ---- hoist Q fragments, pre-scaled by (1/sqrt(d))*log2(e) ----
  const float QSCALE = 0.125f * 1.44269504f;
  const int qrow = wave * 16 + lq;
  bf16x8 qf[2];
#pragma unroll
  for (int ks = 0; ks < 2; ++ks) {
    const float* qp = Qp + (size_t)qrow * DDIM + 8 * g + 32 * ks;
    f32x4 a = *(const f32x4*)qp;
    f32x4 b = *(const f32x4*)(qp + 4);
    bf16x8 t;
#pragma unroll
    for (int j = 0; j < 4; ++j) { t[j] = (__bf16)(a[j] * QSCALE); t[4 + j] = (__bf16)(b[j] * QSCALE); }
    qf[ks] = t;
  }

  const size_t mrow_elems = ((size_t)head * QLEN + (size_t)qblk * QBLK + qrow) * SLEN;
  const unsigned char* mrow8  = Mg + mrow_elems;
  const unsigned*      mrow32 = (const unsigned*)Mg + mrow_elems;

  f32x4 oacc[4];
#pragma unroll
  for (int vt = 0; vt < 4; ++vt) oacc[vt] = (f32x4){0.f, 0.f, 0.f, 0.f};
  float m_run = -INFINITY;   // log2-domain running max
  float l_run = 0.f;

// ---- staging macros (prefetch to regs / convert+write to LDS) ----
#define PREFETCH_KV(S0)                                                        \
  _Pragma("unroll")                                                            \
  for (int it = 0; it < 4; ++it) {                                             \
    int srow = (tid >> 4) + it * 16;                                           \
    kpre[it] = *(const f32x4*)(Kp + (size_t)((S0) + srow) * DDIM + (tid & 15) * 4); \
  }                                                                            \
  _Pragma("unroll")                                                            \
  for (int it = 0; it < 4; ++it) {                                             \
    int vv = (tid >> 4) + it * 16;                                             \
    const float* vp = Vp + (size_t)((S0) + (tid & 15) * 4) * VDIM + vv;        \
    vpre[it][0] = vp[0]; vpre[it][1] = vp[VDIM];                               \
    vpre[it][2] = vp[2 * VDIM]; vpre[it][3] = vp[3 * VDIM];                    \
  }

#define WRITE_KV(BUF)                                                          \
  _Pragma("unroll")                                                            \
  for (int it = 0; it < 4; ++it) {                                             \
    int srow = (tid >> 4) + it * 16;                                           \
    int d0   = (tid & 15) * 4;                                                 \
    bf16x4 kb;                                                                 \
    _Pragma("unroll") for (int j = 0; j < 4; ++j) kb[j] = (__bf16)kpre[it][j]; \
    int off = (srow * 128 + d0 * 2) ^ ((srow & 7) << 4);                       \
    *(u16x4*)((char*)Ksh[BUF] + off) = __builtin_bit_cast(u16x4, kb);          \
  }                                                                            \
  _Pragma("unroll")                                                            \
  for (int it = 0; it < 4; ++it) {                                             \
    int vv = (tid >> 4) + it * 16;                                             \
    int s4 = (tid & 15) * 4;                                                   \
    bf16x4 vb;                                                                 \
    _Pragma("unroll") for (int j = 0; j < 4; ++j) vb[j] = (__bf16)vpre[it][j]; \
    int off = (vv * 128 + s4 * 2) ^ ((vv & 7) << 4);                           \
    *(u16x4*)((char*)Vsh[BUF] + off) = __builtin_bit_cast(u16x4, vb);          \
  }

#define LOAD_MASK(MR, S0)                                                      \
  if (mfmt == 0) {                                                             \
    _Pragma("unroll")                                                          \
    for (int st = 0; st < 4; ++st)                                             \
      MR.w8[st] = *(const unsigned*)(mrow8 + (S0) + 16 * st + 4 * g);          \
  } else {                                                                     \
    _Pragma("unroll")                                                          \
    for (int st = 0; st < 4; ++st)                                             \
      MR.w32[st] = *(const u32x4*)(mrow32 + (S0) + 16 * st + 4 * g);           \
  }

#define CHUNK_BODY(C, CUR, MUSE, MLOAD) {                                      \
  const int s0c = (C) * SBLK;  (void)s0c;                                      \
  const bool hasn = ((C) + 1 < NCHUNK);                                        \
  f32x4 kpre[4]; float vpre[4][4];                                             \
  if (hasn) {                                                                  \
    const int s0n = ((C) + 1) * SBLK;                                          \
    PREFETCH_KV(s0n);                                                          \
    LOAD_MASK(MLOAD, s0n);                                                     \
  }                                                                            \
  /* QK^T from Ksh[CUR] */                                                     \
  f32x4 sacc[4];                                                               \
  _Pragma("unroll")                                                            \
  for (int st = 0; st < 4; ++st) sacc[st] = (f32x4){0.f, 0.f, 0.f, 0.f};       \
  _Pragma("unroll")                                                            \
  for (int st = 0; st < 4; ++st) {                                             \
    int srow = lq + 16 * st;                                                   \
    _Pragma("unroll")                                                          \
    for (int ks = 0; ks < 2; ++ks) {                                           \
      int off = (srow * 128 + (8 * g + 32 * ks) * 2) ^ ((srow & 7) << 4);      \
      bf16x8 kf = *(const bf16x8*)((const char*)Ksh[CUR] + off);               \
      sacc[st] = __builtin_amdgcn_mfma_f32_16x16x32_bf16(kf, qf[ks], sacc[st], 0, 0, 0); \
    }                                                                          \
  }                                                                            \
  /* mask + chunk max (lane scores: s = 16st+4g+r, q=lq) */                    \
  float vals[4][4];                                                            \
  float mloc = -INFINITY;                                                      \
  _Pragma("unroll")                                                            \
  for (int st = 0; st < 4; ++st) {                                             \
    bool keep[4];                                                              \
    if (mfmt == 0) {                                                           \
      _Pragma("unroll")                                                        \
      for (int r = 0; r < 4; ++r) keep[r] = ((MUSE.w8[st] >> (8 * r)) & 0xFFu) != 0u; \
    } else {                                                                   \
      _Pragma("unroll")                                                        \
      for (int r = 0; r < 4; ++r) keep[r] = MUSE.w32[st][r] != 0u;             \
    }                                                                          \
    _Pragma("unroll")                                                          \
    for (int r = 0; r < 4; ++r) {                                              \
      float v = keep[r] ? sacc[st][r] : -1.0e9f;                               \
      vals[st][r] = v;                                                         \
      mloc = fmaxf(mloc, v);                                                   \
    }                                                                          \
  }                                                                            \
  mloc = fmaxf(mloc, __shfl_xor(mloc, 16));                                    \
  mloc = fmaxf(mloc, __shfl_xor(mloc, 32));                                    \
  float m_new = fmaxf(m_run, mloc);                                            \
  float alpha = __builtin_amdgcn_exp2f(m_run - m_new);                         \
  float lsum = 0.f;                                                            \
  _Pragma("unroll")                                                            \
  for (int st = 0; st < 4; ++st) {                                             \
    bf16x4 pb;                                                                 \
    _Pragma("unroll")                                                          \
    for (int r = 0; r < 4; ++r) {                                              \
      float p = __builtin_amdgcn_exp2f(vals[st][r] - m_new);                   \
      lsum += p;                                                               \
      pb[r] = (__bf16)p;                                                       \
    }                                                                          \
    int off = (lq * 128 + (16 * st + 4 * g) * 2) ^ ((lq & 7) << 4);            \
    *(u16x4*)((char*)Psh[wave] + off) = __builtin_bit_cast(u16x4, pb);         \
  }                                                                            \
  lsum += __shfl_xor(lsum, 16);                                                \
  lsum += __shfl_xor(lsum, 32);                                                \
  l_run = l_run * alpha + lsum;                                                \
  m_run = m_new;                                                               \
  _Pragma("unroll")                                                            \
  for (int vt = 0; vt < 4; ++vt) {                                             \
    _Pragma("unroll")                                                          \
    for (int r = 0; r < 4; ++r) oacc[vt][r] *= alpha;                          \
  }                                                                            \
  /* PV: O^T += V^T_tile · P^T */                                              \
  _Pragma("unroll")                                                            \
  for (int ks = 0; ks < 2; ++ks) {                                             \
    int poff = (lq * 128 + (8 * g + 32 * ks) * 2) ^ ((lq & 7) << 4);           \
    bf16x8 pf = *(const bf16x8*)((const char*)Psh[wave] + poff);               \
    _Pragma("unroll")                                                          \
    for (int vt = 0; vt < 4; ++vt) {                                           \
      int vrow = lq + 16 * vt;                                                 \
      int voff = (vrow * 128 + (8 * g + 32 * ks) * 2) ^ ((vrow & 7) << 4);     \
      bf16x8 vf = *(const bf16x8*)((const char*)Vsh[CUR] + voff);              \
      oacc[vt] = __builtin_amdgcn_mfma_f32_16x16x32_bf16(vf, pf, oacc[vt], 0, 0, 0); \
    }                                                                          \
  }                                                                            \
  if (hasn) { WRITE_KV((CUR) ^ 1); }                                           \
  __syncthreads();                                                             \
}

  MaskRegs mA, mB;

  // ---- prologue: stage chunk 0 directly, load its mask ----
  {
    f32x4 kpre[4]; float vpre[4][4];
    PREFETCH_KV(0);
    LOAD_MASK(mA, 0);
    WRITE_KV(0);
    __syncthreads();
  }

  for (int cc = 0; cc < NCHUNK; cc += 2) {
    CHUNK_BODY(cc,     0, mA, mB);
    CHUNK_BODY(cc + 1, 1, mB, mA);
  }

  // ---- epilogue: O = O^T(v,q)/l, store fp32 (lane: q=lq, v=16vt+4g+r) ----
  float inv_l = 1.0f / l_run;
  float* orow = Op + (size_t)qrow * VDIM;
#pragma unroll
  for (int vt = 0; vt < 4; ++vt) {
    f32x4 o;
#pragma unroll
    for (int r = 0; r < 4; ++r) o[r] = oacc[vt][r] * inv_l;
    *(f32x4*)(orow + 16 * vt + 4 * g) = o;
  }
}

extern "C" void kernel_launch(void* const* d_in, const int* in_sizes, int n_in,
                              void* d_out, int out_size, void* d_ws, size_t ws_size,
                              hipStream_t stream) {
  const float* Qg = (const float*)d_in[0];
  const float* Kg = (const float*)d_in[1];
  const float* Vg = (const float*)d_in[2];
  const unsigned char* Mg = (const unsigned char*)d_in[3];
  float* Og = (float*)d_out;
  int* mflag = (int*)d_ws;

  detect_mask_kernel<<<1, 256, 0, stream>>>(Mg, mflag);

  dim3 grid(QLEN / QBLK, NHEADS);
  dim3 block(256);
  attn_fwd_kernel<<<grid, block, 0, stream>>>(Qg, Kg, Vg, Mg, Og, mflag);
}